// Round 1
// baseline (5439.519 us; speedup 1.0000x reference)
//
#include <hip/hip_runtime.h>
#include <hip/hip_bf16.h>

#define BB 4
#define KK 16
#define NN 50000
#define EE 300000
#define RR 64
#define ERE 2048
#define RT 4
#define DD 64
#define LL 4

__device__ __forceinline__ float wsum64(float v) {
#pragma unroll
    for (int off = 32; off > 0; off >>= 1) v += __shfl_xor(v, off, 64);
    return v;
}

// ---------------- Stage A: relation graph conv (single workgroup) -------------
__global__ __launch_bounds__(1024) void rel_stage(
    const int* __restrict__ rel_edge_index, const int* __restrict__ rel_edge_type,
    const int* __restrict__ batch_triples,
    const float* __restrict__ rel_emb, const float* __restrict__ rel_W,
    const float* __restrict__ rel_b, const float* __restrict__ rel_g,
    const float* __restrict__ rel_beta,
    float* __restrict__ xrel,   // B*R*D (becomes relation_repr)
    float* __restrict__ query,  // B*D
    float* __restrict__ x_ent)  // B*N*D (seed boundary)
{
    __shared__ float ls_agg[BB * RR * DD];  // 64 KB
    const int tid = threadIdx.x;
    const int wid = tid >> 6, lane = tid & 63;

    // x = boundary_r : x[b][r0[b]][:] = 1
    for (int i = tid; i < BB * RR * DD; i += 1024) {
        int b = i / (RR * DD);
        int r = (i % (RR * DD)) / DD;
        int r0 = batch_triples[(b * KK) * 3 + 2];
        xrel[i] = (r == r0) ? 1.0f : 0.0f;
    }
    __syncthreads();

    for (int l = 0; l < LL; ++l) {
        for (int i = tid; i < BB * RR * DD; i += 1024) ls_agg[i] = 0.0f;
        __syncthreads();
        // messages: wave per (b, e)
        for (int idx = wid; idx < BB * ERE; idx += 16) {
            int b = idx / ERE, e = idx - b * ERE;
            int s = rel_edge_index[e];
            int dd = rel_edge_index[ERE + e];
            int et = rel_edge_type[e];
            float xv = xrel[(b * RR + s) * DD + lane];
            float rv = rel_emb[(l * RT + et) * DD + lane];
            atomicAdd(&ls_agg[(b * RR + dd) * DD + lane], xv * rv);
        }
        __syncthreads();
        // + boundary
        if (tid < BB * DD) {
            int b = tid / DD, d = tid - b * DD;
            int r0 = batch_triples[(b * KK) * 3 + 2];
            atomicAdd(&ls_agg[(b * RR + r0) * DD + d], 1.0f);
        }
        __syncthreads();
        // dense + LN + relu + residual, wave per row
        const float* W = &rel_W[l * 2 * DD * DD];
        for (int row = wid; row < BB * RR; row += 16) {
            const float* xr = &xrel[row * DD];
            const float* ar = &ls_agg[row * DD];
            float acc = rel_b[l * DD + lane];
#pragma unroll 8
            for (int k = 0; k < DD; ++k) acc += xr[k] * W[k * DD + lane];
#pragma unroll 8
            for (int k = 0; k < DD; ++k) acc += ar[k] * W[(DD + k) * DD + lane];
            float m = wsum64(acc) * (1.0f / DD);
            float c = acc - m;
            float v = wsum64(c * c) * (1.0f / DD);
            float o = c * rsqrtf(v + 1e-5f) * rel_g[l * DD + lane] + rel_beta[l * DD + lane];
            o = fmaxf(o, 0.0f) + xr[lane];
            xrel[row * DD + lane] = o;
        }
        __syncthreads();
    }

    // query[b] = relation_repr[b, r0[b]]; seed x_ent boundary
    if (tid < BB * DD) {
        int b = tid / DD, d = tid - b * DD;
        int r0 = batch_triples[(b * KK) * 3 + 2];
        int h0 = batch_triples[(b * KK) * 3 + 0];
        float q = xrel[(b * RR + r0) * DD + d];
        query[b * DD + d] = q;
        x_ent[((size_t)b * NN + h0) * DD + d] = q;
    }
}

// ---------------- rel projection per entity layer ----------------------------
__global__ __launch_bounds__(256) void rel_proj(
    const float* __restrict__ rel_repr,
    const float* __restrict__ W1, const float* __restrict__ b1,
    const float* __restrict__ W2, const float* __restrict__ b2,
    float* __restrict__ rel_buf)
{
    int row = (blockIdx.x * 256 + threadIdx.x) >> 6;  // 0..B*R-1
    int lane = threadIdx.x & 63;
    if (row >= BB * RR) return;
    const float* xr = &rel_repr[row * DD];
    float h = b1[lane];
#pragma unroll 8
    for (int k = 0; k < DD; ++k) h += xr[k] * W1[k * DD + lane];
    h = fmaxf(h, 0.0f);
    float o = b2[lane];
#pragma unroll 8
    for (int k = 0; k < DD; ++k) o += __shfl(h, k, 64) * W2[k * DD + lane];
    rel_buf[row * DD + lane] = o;
}

// ---------------- boundary add (agg += boundary) -----------------------------
__global__ void boundary_add(const int* __restrict__ bt,
                             const float* __restrict__ query,
                             float* __restrict__ agg)
{
    int b = blockIdx.x, d = threadIdx.x;
    int h0 = bt[b * KK * 3];
    agg[((size_t)b * NN + h0) * DD + d] += query[b * DD + d];
}

// ---------------- message scatter: wave per (b, e) ---------------------------
__global__ __launch_bounds__(256) void scatter_msg(
    const int* __restrict__ edge_index, const int* __restrict__ edge_type,
    const float* __restrict__ x, const float* __restrict__ rel_buf,
    float* __restrict__ agg)
{
    int gw = (int)((blockIdx.x * 256 + threadIdx.x) >> 6);  // 0..B*E-1
    int lane = threadIdx.x & 63;
    if (gw >= BB * EE) return;
    int b = gw / EE, e = gw - b * EE;
    int s = edge_index[e];
    int dd = edge_index[EE + e];
    int et = edge_type[e];
    float xv = x[((size_t)b * NN + s) * DD + lane];
    float rv = rel_buf[(b * RR + et) * DD + lane];
    atomicAdd(&agg[((size_t)b * NN + dd) * DD + lane], xv * rv);
}

// ---------------- dense + LN + relu + residual, wave per row -----------------
__global__ __launch_bounds__(256) void ent_dense(
    const float* __restrict__ W, const float* __restrict__ bias,
    const float* __restrict__ g, const float* __restrict__ beta,
    float* __restrict__ x, const float* __restrict__ agg)
{
    int row = (int)((blockIdx.x * 256 + threadIdx.x) >> 6);  // 0..B*N-1
    int lane = threadIdx.x & 63;
    if (row >= BB * NN) return;
    size_t base = (size_t)row * DD;
    float xv = x[base + lane];
    float av = agg[base + lane];
    float acc = bias[lane];
#pragma unroll 8
    for (int k = 0; k < DD; ++k) {
        acc += __shfl(xv, k, 64) * W[k * DD + lane];
        acc += __shfl(av, k, 64) * W[(DD + k) * DD + lane];
    }
    float m = wsum64(acc) * (1.0f / DD);
    float c = acc - m;
    float v = wsum64(c * c) * (1.0f / DD);
    float o = c * rsqrtf(v + 1e-5f) * g[lane] + beta[lane];
    o = fmaxf(o, 0.0f) + xv;
    x[base + lane] = o;
}

// ---------------- readout ----------------------------------------------------
__global__ __launch_bounds__(128) void readout(
    const int* __restrict__ bt, const float* __restrict__ x,
    const float* __restrict__ query,
    const float* __restrict__ W1, const float* __restrict__ b1,
    const float* __restrict__ W2, const float* __restrict__ b2,
    float* __restrict__ out)
{
    int b = blockIdx.x / KK, k = blockIdx.x - b * KK;
    int t = bt[(b * KK + k) * 3 + 1];
    __shared__ float feat[2 * DD];
    __shared__ float red[2 * DD];
    int j = threadIdx.x;
    if (j < DD) feat[j] = x[((size_t)b * NN + t) * DD + j];
    else        feat[j] = query[b * DD + (j - DD)];
    __syncthreads();
    float h = b1[j];
#pragma unroll 8
    for (int i = 0; i < 2 * DD; ++i) h += feat[i] * W1[i * 2 * DD + j];
    h = fmaxf(h, 0.0f);
    red[j] = h * W2[j];
    __syncthreads();
    for (int s = 64; s > 0; s >>= 1) {
        if (j < s) red[j] += red[j + s];
        __syncthreads();
    }
    if (j == 0) out[blockIdx.x] = red[0] + b2[0];
}

extern "C" void kernel_launch(void* const* d_in, const int* in_sizes, int n_in,
                              void* d_out, int out_size, void* d_ws, size_t ws_size,
                              hipStream_t stream) {
    const int*   edge_index     = (const int*)d_in[0];
    const int*   edge_type      = (const int*)d_in[1];
    const int*   rel_edge_index = (const int*)d_in[2];
    const int*   rel_edge_type  = (const int*)d_in[3];
    const int*   batch_triples  = (const int*)d_in[4];
    const float* rel_emb        = (const float*)d_in[5];
    const float* rel_W          = (const float*)d_in[6];
    const float* rel_b          = (const float*)d_in[7];
    const float* rel_g          = (const float*)d_in[8];
    const float* rel_beta       = (const float*)d_in[9];
    const float* proj_W1        = (const float*)d_in[10];
    const float* proj_b1        = (const float*)d_in[11];
    const float* proj_W2        = (const float*)d_in[12];
    const float* proj_b2        = (const float*)d_in[13];
    const float* ent_W          = (const float*)d_in[14];
    const float* ent_b          = (const float*)d_in[15];
    const float* ent_g          = (const float*)d_in[16];
    const float* ent_beta       = (const float*)d_in[17];
    const float* mlp_W1         = (const float*)d_in[18];
    const float* mlp_b1         = (const float*)d_in[19];
    const float* mlp_W2         = (const float*)d_in[20];
    const float* mlp_b2         = (const float*)d_in[21];

    float* ws = (float*)d_ws;
    float* x_ent    = ws;                                   // B*N*D
    float* agg_ent  = x_ent   + (size_t)BB * NN * DD;       // B*N*D
    float* rel_repr = agg_ent + (size_t)BB * NN * DD;       // B*R*D
    float* rel_buf  = rel_repr + BB * RR * DD;              // B*R*D
    float* query    = rel_buf  + BB * RR * DD;              // B*D

    hipMemsetAsync(x_ent, 0, sizeof(float) * (size_t)BB * NN * DD, stream);
    rel_stage<<<1, 1024, 0, stream>>>(rel_edge_index, rel_edge_type, batch_triples,
                                      rel_emb, rel_W, rel_b, rel_g, rel_beta,
                                      rel_repr, query, x_ent);

    for (int l = 0; l < LL; ++l) {
        rel_proj<<<(BB * RR * 64) / 256, 256, 0, stream>>>(
            rel_repr, proj_W1 + l * DD * DD, proj_b1 + l * DD,
            proj_W2 + l * DD * DD, proj_b2 + l * DD, rel_buf);
        hipMemsetAsync(agg_ent, 0, sizeof(float) * (size_t)BB * NN * DD, stream);
        boundary_add<<<BB, DD, 0, stream>>>(batch_triples, query, agg_ent);
        scatter_msg<<<(BB * EE) / 4, 256, 0, stream>>>(edge_index, edge_type,
                                                       x_ent, rel_buf, agg_ent);
        ent_dense<<<(BB * NN) / 4, 256, 0, stream>>>(
            ent_W + l * 2 * DD * DD, ent_b + l * DD, ent_g + l * DD,
            ent_beta + l * DD, x_ent, agg_ent);
    }

    readout<<<BB * KK, 2 * DD, 0, stream>>>(batch_triples, x_ent, query,
                                            mlp_W1, mlp_b1, mlp_W2, mlp_b2,
                                            (float*)d_out);
}

// Round 2
// 2411.003 us; speedup vs baseline: 2.2561x; 2.2561x over previous
//
#include <hip/hip_runtime.h>
#include <hip/hip_bf16.h>

#define BB 4
#define KK 16
#define NN 50000
#define EE 300000
#define RR 64
#define ERE 2048
#define RT 4
#define DD 64
#define LL 4

__device__ __forceinline__ float wsum64(float v) {
#pragma unroll
    for (int off = 32; off > 0; off >>= 1) v += __shfl_xor(v, off, 64);
    return v;
}

// ---------------- relation stage: init x = boundary_r ------------------------
__global__ __launch_bounds__(256) void rel_init(
    const int* __restrict__ bt, float* __restrict__ xrel)
{
    int i = blockIdx.x * 256 + threadIdx.x;
    if (i >= BB * RR * DD) return;
    int b = i / (RR * DD);
    int r = (i % (RR * DD)) / DD;
    int r0 = bt[(b * KK) * 3 + 2];
    xrel[i] = (r == r0) ? 1.0f : 0.0f;
}

// ---------------- relation stage: message scatter ----------------------------
__global__ __launch_bounds__(256) void rel_scatter(
    const int* __restrict__ rel_edge_index, const int* __restrict__ rel_edge_type,
    const float* __restrict__ xrel, const float* __restrict__ rel_emb_l,
    float* __restrict__ rel_agg)
{
    int gw = (int)((blockIdx.x * 256 + threadIdx.x) >> 6);  // 0..B*ER-1
    int lane = threadIdx.x & 63;
    if (gw >= BB * ERE) return;
    int b = gw / ERE, e = gw - b * ERE;
    int s = rel_edge_index[e];
    int dd = rel_edge_index[ERE + e];
    int et = rel_edge_type[e];
    float xv = xrel[(b * RR + s) * DD + lane];
    float rv = rel_emb_l[et * DD + lane];
    atomicAdd(&rel_agg[(b * RR + dd) * DD + lane], xv * rv);
}

// ---------------- relation stage: dense + LN + relu + residual ---------------
__global__ __launch_bounds__(256) void rel_dense(
    const int* __restrict__ bt,
    const float* __restrict__ W, const float* __restrict__ bias,
    const float* __restrict__ g, const float* __restrict__ beta,
    float* __restrict__ xrel, const float* __restrict__ rel_agg)
{
    int row = (int)((blockIdx.x * 256 + threadIdx.x) >> 6);  // 0..B*R-1
    int lane = threadIdx.x & 63;
    if (row >= BB * RR) return;
    int b = row / RR, r = row - b * RR;
    int r0 = bt[(b * KK) * 3 + 2];
    float xv = xrel[row * DD + lane];
    float av = rel_agg[row * DD + lane] + ((r == r0) ? 1.0f : 0.0f);
    float acc = bias[lane];
#pragma unroll 8
    for (int k = 0; k < DD; ++k) {
        acc += __shfl(xv, k, 64) * W[k * DD + lane];
        acc += __shfl(av, k, 64) * W[(DD + k) * DD + lane];
    }
    float m = wsum64(acc) * (1.0f / DD);
    float c = acc - m;
    float v = wsum64(c * c) * (1.0f / DD);
    float o = c * rsqrtf(v + 1e-5f) * g[lane] + beta[lane];
    o = fmaxf(o, 0.0f) + xv;
    xrel[row * DD + lane] = o;
}

// ---------------- relation stage: query + entity boundary seed ---------------
__global__ __launch_bounds__(256) void rel_finish(
    const int* __restrict__ bt, const float* __restrict__ xrel,
    float* __restrict__ query, float* __restrict__ x_ent)
{
    int i = threadIdx.x;  // 0..255 = B*D
    int b = i / DD, d = i - b * DD;
    int r0 = bt[(b * KK) * 3 + 2];
    int h0 = bt[(b * KK) * 3 + 0];
    float q = xrel[(b * RR + r0) * DD + d];
    query[b * DD + d] = q;
    x_ent[((size_t)b * NN + h0) * DD + d] = q;
}

// ---------------- rel projection per entity layer ----------------------------
__global__ __launch_bounds__(256) void rel_proj(
    const float* __restrict__ rel_repr,
    const float* __restrict__ W1, const float* __restrict__ b1,
    const float* __restrict__ W2, const float* __restrict__ b2,
    float* __restrict__ rel_buf)
{
    int row = (blockIdx.x * 256 + threadIdx.x) >> 6;  // 0..B*R-1
    int lane = threadIdx.x & 63;
    if (row >= BB * RR) return;
    const float* xr = &rel_repr[row * DD];
    float h = b1[lane];
#pragma unroll 8
    for (int k = 0; k < DD; ++k) h += xr[k] * W1[k * DD + lane];
    h = fmaxf(h, 0.0f);
    float o = b2[lane];
#pragma unroll 8
    for (int k = 0; k < DD; ++k) o += __shfl(h, k, 64) * W2[k * DD + lane];
    rel_buf[row * DD + lane] = o;
}

// ---------------- boundary add (agg += boundary) -----------------------------
__global__ void boundary_add(const int* __restrict__ bt,
                             const float* __restrict__ query,
                             float* __restrict__ agg)
{
    int b = blockIdx.x, d = threadIdx.x;
    int h0 = bt[b * KK * 3];
    agg[((size_t)b * NN + h0) * DD + d] += query[b * DD + d];
}

// ---------------- message scatter: wave per (b, e) ---------------------------
__global__ __launch_bounds__(256) void scatter_msg(
    const int* __restrict__ edge_index, const int* __restrict__ edge_type,
    const float* __restrict__ x, const float* __restrict__ rel_buf,
    float* __restrict__ agg)
{
    int gw = (int)((blockIdx.x * 256 + threadIdx.x) >> 6);  // 0..B*E-1
    int lane = threadIdx.x & 63;
    if (gw >= BB * EE) return;
    int b = gw / EE, e = gw - b * EE;
    int s = edge_index[e];
    int dd = edge_index[EE + e];
    int et = edge_type[e];
    float xv = x[((size_t)b * NN + s) * DD + lane];
    float rv = rel_buf[(b * RR + et) * DD + lane];
    atomicAdd(&agg[((size_t)b * NN + dd) * DD + lane], xv * rv);
}

// ---------------- dense + LN + relu + residual, wave per row -----------------
__global__ __launch_bounds__(256) void ent_dense(
    const float* __restrict__ W, const float* __restrict__ bias,
    const float* __restrict__ g, const float* __restrict__ beta,
    float* __restrict__ x, const float* __restrict__ agg)
{
    int row = (int)((blockIdx.x * 256 + threadIdx.x) >> 6);  // 0..B*N-1
    int lane = threadIdx.x & 63;
    if (row >= BB * NN) return;
    size_t base = (size_t)row * DD;
    float xv = x[base + lane];
    float av = agg[base + lane];
    float acc = bias[lane];
#pragma unroll 8
    for (int k = 0; k < DD; ++k) {
        acc += __shfl(xv, k, 64) * W[k * DD + lane];
        acc += __shfl(av, k, 64) * W[(DD + k) * DD + lane];
    }
    float m = wsum64(acc) * (1.0f / DD);
    float c = acc - m;
    float v = wsum64(c * c) * (1.0f / DD);
    float o = c * rsqrtf(v + 1e-5f) * g[lane] + beta[lane];
    o = fmaxf(o, 0.0f) + xv;
    x[base + lane] = o;
}

// ---------------- readout ----------------------------------------------------
__global__ __launch_bounds__(128) void readout(
    const int* __restrict__ bt, const float* __restrict__ x,
    const float* __restrict__ query,
    const float* __restrict__ W1, const float* __restrict__ b1,
    const float* __restrict__ W2, const float* __restrict__ b2,
    float* __restrict__ out)
{
    int b = blockIdx.x / KK, k = blockIdx.x - b * KK;
    int t = bt[(b * KK + k) * 3 + 1];
    __shared__ float feat[2 * DD];
    __shared__ float red[2 * DD];
    int j = threadIdx.x;
    if (j < DD) feat[j] = x[((size_t)b * NN + t) * DD + j];
    else        feat[j] = query[b * DD + (j - DD)];
    __syncthreads();
    float h = b1[j];
#pragma unroll 8
    for (int i = 0; i < 2 * DD; ++i) h += feat[i] * W1[i * 2 * DD + j];
    h = fmaxf(h, 0.0f);
    red[j] = h * W2[j];
    __syncthreads();
    for (int s = 64; s > 0; s >>= 1) {
        if (j < s) red[j] += red[j + s];
        __syncthreads();
    }
    if (j == 0) out[blockIdx.x] = red[0] + b2[0];
}

extern "C" void kernel_launch(void* const* d_in, const int* in_sizes, int n_in,
                              void* d_out, int out_size, void* d_ws, size_t ws_size,
                              hipStream_t stream) {
    const int*   edge_index     = (const int*)d_in[0];
    const int*   edge_type      = (const int*)d_in[1];
    const int*   rel_edge_index = (const int*)d_in[2];
    const int*   rel_edge_type  = (const int*)d_in[3];
    const int*   batch_triples  = (const int*)d_in[4];
    const float* rel_emb        = (const float*)d_in[5];
    const float* rel_W          = (const float*)d_in[6];
    const float* rel_b          = (const float*)d_in[7];
    const float* rel_g          = (const float*)d_in[8];
    const float* rel_beta       = (const float*)d_in[9];
    const float* proj_W1        = (const float*)d_in[10];
    const float* proj_b1        = (const float*)d_in[11];
    const float* proj_W2        = (const float*)d_in[12];
    const float* proj_b2        = (const float*)d_in[13];
    const float* ent_W          = (const float*)d_in[14];
    const float* ent_b          = (const float*)d_in[15];
    const float* ent_g          = (const float*)d_in[16];
    const float* ent_beta       = (const float*)d_in[17];
    const float* mlp_W1         = (const float*)d_in[18];
    const float* mlp_b1         = (const float*)d_in[19];
    const float* mlp_W2         = (const float*)d_in[20];
    const float* mlp_b2         = (const float*)d_in[21];

    float* ws = (float*)d_ws;
    float* x_ent    = ws;                                   // B*N*D
    float* agg_ent  = x_ent    + (size_t)BB * NN * DD;      // B*N*D
    float* rel_repr = agg_ent  + (size_t)BB * NN * DD;      // B*R*D
    float* rel_buf  = rel_repr + BB * RR * DD;              // B*R*D
    float* rel_agg  = rel_buf  + BB * RR * DD;              // B*R*D
    float* query    = rel_agg  + BB * RR * DD;              // B*D

    // ---- relation stage (multi-CU, per-layer mini kernels) ----
    rel_init<<<(BB * RR * DD + 255) / 256, 256, 0, stream>>>(batch_triples, rel_repr);
    for (int l = 0; l < LL; ++l) {
        hipMemsetAsync(rel_agg, 0, sizeof(float) * BB * RR * DD, stream);
        rel_scatter<<<(BB * ERE) / 4, 256, 0, stream>>>(
            rel_edge_index, rel_edge_type, rel_repr,
            rel_emb + l * RT * DD, rel_agg);
        rel_dense<<<(BB * RR) / 4, 256, 0, stream>>>(
            batch_triples, rel_W + l * 2 * DD * DD, rel_b + l * DD,
            rel_g + l * DD, rel_beta + l * DD, rel_repr, rel_agg);
    }
    hipMemsetAsync(x_ent, 0, sizeof(float) * (size_t)BB * NN * DD, stream);
    rel_finish<<<1, 256, 0, stream>>>(batch_triples, rel_repr, query, x_ent);

    // ---- entity stage ----
    for (int l = 0; l < LL; ++l) {
        rel_proj<<<(BB * RR * 64) / 256, 256, 0, stream>>>(
            rel_repr, proj_W1 + l * DD * DD, proj_b1 + l * DD,
            proj_W2 + l * DD * DD, proj_b2 + l * DD, rel_buf);
        hipMemsetAsync(agg_ent, 0, sizeof(float) * (size_t)BB * NN * DD, stream);
        boundary_add<<<BB, DD, 0, stream>>>(batch_triples, query, agg_ent);
        scatter_msg<<<(BB * EE) / 4, 256, 0, stream>>>(edge_index, edge_type,
                                                       x_ent, rel_buf, agg_ent);
        ent_dense<<<(BB * NN) / 4, 256, 0, stream>>>(
            ent_W + l * 2 * DD * DD, ent_b + l * DD, ent_g + l * DD,
            ent_beta + l * DD, x_ent, agg_ent);
    }

    readout<<<BB * KK, 2 * DD, 0, stream>>>(batch_triples, x_ent, query,
                                            mlp_W1, mlp_b1, mlp_W2, mlp_b2,
                                            (float*)d_out);
}

// Round 3
// 1134.981 us; speedup vs baseline: 4.7926x; 2.1243x over previous
//
#include <hip/hip_runtime.h>
#include <hip/hip_bf16.h>

#define BB 4
#define KK 16
#define NN 50000
#define EE 300000
#define RR 64
#define ERE 2048
#define RT 4
#define DD 64
#define LL 4

__device__ __forceinline__ float wsum64(float v) {
#pragma unroll
    for (int off = 32; off > 0; off >>= 1) v += __shfl_xor(v, off, 64);
    return v;
}

// ==================== CSR build (once per call) ==============================
__global__ __launch_bounds__(256) void csr_hist(
    const int* __restrict__ edge_index, int* __restrict__ deg)
{
    int e = blockIdx.x * 256 + threadIdx.x;
    if (e < EE) atomicAdd(&deg[edge_index[EE + e]], 1);
}

__global__ __launch_bounds__(1024) void csr_scan(
    const int* __restrict__ deg, int* __restrict__ rowptr, int* __restrict__ cursor)
{
    __shared__ int psum[1024];
    const int t = threadIdx.x;
    const int CH = (NN + 1023) / 1024;  // 49
    int base = t * CH;
    int s = 0;
    for (int i = 0; i < CH; ++i) {
        int idx = base + i;
        if (idx < NN) s += deg[idx];
    }
    psum[t] = s;
    __syncthreads();
    for (int off = 1; off < 1024; off <<= 1) {
        int v = (t >= off) ? psum[t - off] : 0;
        __syncthreads();
        psum[t] += v;
        __syncthreads();
    }
    int run = (t == 0) ? 0 : psum[t - 1];
    for (int i = 0; i < CH; ++i) {
        int idx = base + i;
        if (idx < NN) {
            rowptr[idx] = run;
            cursor[idx] = run;
            run += deg[idx];
        }
    }
    if (t == 0) rowptr[NN] = EE;
}

__global__ __launch_bounds__(256) void csr_fill(
    const int* __restrict__ edge_index, const int* __restrict__ edge_type,
    int* __restrict__ cursor, int* __restrict__ pack)
{
    int e = blockIdx.x * 256 + threadIdx.x;
    if (e >= EE) return;
    int s = edge_index[e];
    int d = edge_index[EE + e];
    int t = edge_type[e];
    int pos = atomicAdd(&cursor[d], 1);
    pack[pos] = s | (t << 16);  // src < 2^16, et < 64
}

// ==================== relation stage =========================================
__global__ __launch_bounds__(256) void rel_init(
    const int* __restrict__ bt, float* __restrict__ xrel)
{
    int i = blockIdx.x * 256 + threadIdx.x;
    if (i >= BB * RR * DD) return;
    int b = i / (RR * DD);
    int r = (i % (RR * DD)) / DD;
    int r0 = bt[(b * KK) * 3 + 2];
    xrel[i] = (r == r0) ? 1.0f : 0.0f;
}

__global__ __launch_bounds__(256) void rel_scatter(
    const int* __restrict__ rel_edge_index, const int* __restrict__ rel_edge_type,
    const float* __restrict__ xrel, const float* __restrict__ rel_emb_l,
    float* __restrict__ rel_agg)
{
    int gw = (int)((blockIdx.x * 256 + threadIdx.x) >> 6);  // 0..B*ER-1
    int lane = threadIdx.x & 63;
    if (gw >= BB * ERE) return;
    int b = gw / ERE, e = gw - b * ERE;
    int s = rel_edge_index[e];
    int dd = rel_edge_index[ERE + e];
    int et = rel_edge_type[e];
    float xv = xrel[(b * RR + s) * DD + lane];
    float rv = rel_emb_l[et * DD + lane];
    atomicAdd(&rel_agg[(b * RR + dd) * DD + lane], xv * rv);
}

__global__ __launch_bounds__(256) void rel_dense(
    const int* __restrict__ bt,
    const float* __restrict__ W, const float* __restrict__ bias,
    const float* __restrict__ g, const float* __restrict__ beta,
    float* __restrict__ xrel, const float* __restrict__ rel_agg)
{
    int row = (int)((blockIdx.x * 256 + threadIdx.x) >> 6);  // 0..B*R-1
    int lane = threadIdx.x & 63;
    if (row >= BB * RR) return;
    int b = row / RR, r = row - b * RR;
    int r0 = bt[(b * KK) * 3 + 2];
    float xv = xrel[row * DD + lane];
    float av = rel_agg[row * DD + lane] + ((r == r0) ? 1.0f : 0.0f);
    float acc = bias[lane];
#pragma unroll 8
    for (int k = 0; k < DD; ++k) {
        acc += __shfl(xv, k, 64) * W[k * DD + lane];
        acc += __shfl(av, k, 64) * W[(DD + k) * DD + lane];
    }
    float m = wsum64(acc) * (1.0f / DD);
    float c = acc - m;
    float v = wsum64(c * c) * (1.0f / DD);
    float o = c * rsqrtf(v + 1e-5f) * g[lane] + beta[lane];
    o = fmaxf(o, 0.0f) + xv;
    xrel[row * DD + lane] = o;
}

__global__ __launch_bounds__(256) void rel_finish(
    const int* __restrict__ bt, const float* __restrict__ xrel,
    float* __restrict__ query, float* __restrict__ x_ent)
{
    int i = threadIdx.x;  // 0..255 = B*D
    int b = i / DD, d = i - b * DD;
    int r0 = bt[(b * KK) * 3 + 2];
    int h0 = bt[(b * KK) * 3 + 0];
    float q = xrel[(b * RR + r0) * DD + d];
    query[b * DD + d] = q;
    x_ent[((size_t)b * NN + h0) * DD + d] = q;
}

// ==================== entity stage ===========================================
__global__ __launch_bounds__(256) void rel_proj(
    const float* __restrict__ rel_repr,
    const float* __restrict__ W1, const float* __restrict__ b1,
    const float* __restrict__ W2, const float* __restrict__ b2,
    float* __restrict__ rel_buf)
{
    int row = (blockIdx.x * 256 + threadIdx.x) >> 6;  // 0..B*R-1
    int lane = threadIdx.x & 63;
    if (row >= BB * RR) return;
    const float* xr = &rel_repr[row * DD];
    float h = b1[lane];
#pragma unroll 8
    for (int k = 0; k < DD; ++k) h += xr[k] * W1[k * DD + lane];
    h = fmaxf(h, 0.0f);
    float o = b2[lane];
#pragma unroll 8
    for (int k = 0; k < DD; ++k) o += __shfl(h, k, 64) * W2[k * DD + lane];
    rel_buf[row * DD + lane] = o;
}

// gather: one wave per (b, v) — atomic-free aggregation + boundary fold-in
__global__ __launch_bounds__(256) void gather_agg(
    const int* __restrict__ rowptr, const int* __restrict__ pack,
    const int* __restrict__ bt,
    const float* __restrict__ x, const float* __restrict__ rel_buf,
    const float* __restrict__ query, float* __restrict__ agg)
{
    int gw = blockIdx.x * 4 + (int)(threadIdx.x >> 6);
    int lane = threadIdx.x & 63;
    if (gw >= BB * NN) return;
    int b = gw / NN, v = gw - b * NN;
    int beg = rowptr[v], end = rowptr[v + 1];
    const float* xb = x + (size_t)b * NN * DD;
    const float* rb = rel_buf + b * RR * DD;
    float acc = 0.0f;
    int j = beg;
    for (; j + 1 < end; j += 2) {
        int p0 = pack[j], p1 = pack[j + 1];
        float m0 = xb[(p0 & 0xFFFF) * DD + lane] * rb[(p0 >> 16) * DD + lane];
        float m1 = xb[(p1 & 0xFFFF) * DD + lane] * rb[(p1 >> 16) * DD + lane];
        acc += m0 + m1;
    }
    if (j < end) {
        int p0 = pack[j];
        acc += xb[(p0 & 0xFFFF) * DD + lane] * rb[(p0 >> 16) * DD + lane];
    }
    int h0 = bt[b * KK * 3];
    if (v == h0) acc += query[b * DD + lane];
    agg[(size_t)gw * DD + lane] = acc;
}

// dense: W column in 128 VGPRs, uniform float4 row loads, no W reloads/shfl
#define DENSE_BLOCKS 768
__global__ __launch_bounds__(256) void ent_dense2(
    const float* __restrict__ W, const float* __restrict__ bias,
    const float* __restrict__ g, const float* __restrict__ beta,
    float* __restrict__ x, const float* __restrict__ agg)
{
    int lane = threadIdx.x & 63;
    float w[128];
#pragma unroll
    for (int k = 0; k < 128; ++k) w[k] = W[k * DD + lane];
    float bi = bias[lane], gg = g[lane], be = beta[lane];
    int gw = blockIdx.x * 4 + (int)(threadIdx.x >> 6);
    const int NWAVE = DENSE_BLOCKS * 4;
    for (int row = gw; row < BB * NN; row += NWAVE) {
        int urow = __builtin_amdgcn_readfirstlane(row);
        const float* xr = x + (size_t)urow * DD;
        const float* ar = agg + (size_t)urow * DD;
        float xv = xr[lane];
        const float4* x4 = (const float4*)xr;
        const float4* a4 = (const float4*)ar;
        float acc0 = bi, acc1 = 0.0f;
#pragma unroll
        for (int q = 0; q < 16; ++q) {
            float4 c = x4[q];
            acc0 += c.x * w[4 * q + 0];
            acc1 += c.y * w[4 * q + 1];
            acc0 += c.z * w[4 * q + 2];
            acc1 += c.w * w[4 * q + 3];
        }
#pragma unroll
        for (int q = 0; q < 16; ++q) {
            float4 c = a4[q];
            acc0 += c.x * w[64 + 4 * q + 0];
            acc1 += c.y * w[64 + 4 * q + 1];
            acc0 += c.z * w[64 + 4 * q + 2];
            acc1 += c.w * w[64 + 4 * q + 3];
        }
        float acc = acc0 + acc1;
        float m = wsum64(acc) * (1.0f / DD);
        float c2 = acc - m;
        float vv = wsum64(c2 * c2) * (1.0f / DD);
        float o = c2 * rsqrtf(vv + 1e-5f) * gg + be;
        o = fmaxf(o, 0.0f) + xv;
        x[(size_t)urow * DD + lane] = o;
    }
}

// ==================== readout ================================================
__global__ __launch_bounds__(128) void readout(
    const int* __restrict__ bt, const float* __restrict__ x,
    const float* __restrict__ query,
    const float* __restrict__ W1, const float* __restrict__ b1,
    const float* __restrict__ W2, const float* __restrict__ b2,
    float* __restrict__ out)
{
    int b = blockIdx.x / KK, k = blockIdx.x - b * KK;
    int t = bt[(b * KK + k) * 3 + 1];
    __shared__ float feat[2 * DD];
    __shared__ float red[2 * DD];
    int j = threadIdx.x;
    if (j < DD) feat[j] = x[((size_t)b * NN + t) * DD + j];
    else        feat[j] = query[b * DD + (j - DD)];
    __syncthreads();
    float h = b1[j];
#pragma unroll 8
    for (int i = 0; i < 2 * DD; ++i) h += feat[i] * W1[i * 2 * DD + j];
    h = fmaxf(h, 0.0f);
    red[j] = h * W2[j];
    __syncthreads();
    for (int s = 64; s > 0; s >>= 1) {
        if (j < s) red[j] += red[j + s];
        __syncthreads();
    }
    if (j == 0) out[blockIdx.x] = red[0] + b2[0];
}

extern "C" void kernel_launch(void* const* d_in, const int* in_sizes, int n_in,
                              void* d_out, int out_size, void* d_ws, size_t ws_size,
                              hipStream_t stream) {
    const int*   edge_index     = (const int*)d_in[0];
    const int*   edge_type      = (const int*)d_in[1];
    const int*   rel_edge_index = (const int*)d_in[2];
    const int*   rel_edge_type  = (const int*)d_in[3];
    const int*   batch_triples  = (const int*)d_in[4];
    const float* rel_emb        = (const float*)d_in[5];
    const float* rel_W          = (const float*)d_in[6];
    const float* rel_b          = (const float*)d_in[7];
    const float* rel_g          = (const float*)d_in[8];
    const float* rel_beta       = (const float*)d_in[9];
    const float* proj_W1        = (const float*)d_in[10];
    const float* proj_b1        = (const float*)d_in[11];
    const float* proj_W2        = (const float*)d_in[12];
    const float* proj_b2        = (const float*)d_in[13];
    const float* ent_W          = (const float*)d_in[14];
    const float* ent_b          = (const float*)d_in[15];
    const float* ent_g          = (const float*)d_in[16];
    const float* ent_beta       = (const float*)d_in[17];
    const float* mlp_W1         = (const float*)d_in[18];
    const float* mlp_b1         = (const float*)d_in[19];
    const float* mlp_W2         = (const float*)d_in[20];
    const float* mlp_b2         = (const float*)d_in[21];

    float* ws = (float*)d_ws;
    float* x_ent    = ws;                                   // B*N*D
    float* agg_ent  = x_ent    + (size_t)BB * NN * DD;      // B*N*D
    float* rel_repr = agg_ent  + (size_t)BB * NN * DD;      // B*R*D
    float* rel_buf  = rel_repr + BB * RR * DD;              // B*R*D
    float* rel_agg  = rel_buf  + BB * RR * DD;              // B*R*D
    float* query    = rel_agg  + BB * RR * DD;              // B*D
    int*   deg      = (int*)(query + BB * DD);              // N
    int*   rowptr   = deg + NN;                             // N+1
    int*   cursor   = rowptr + NN + 1;                      // N
    int*   pack     = cursor + NN;                          // E

    // ---- CSR build (per-call, deterministic up to f32 sum order) ----
    hipMemsetAsync(deg, 0, sizeof(int) * NN, stream);
    csr_hist<<<(EE + 255) / 256, 256, 0, stream>>>(edge_index, deg);
    csr_scan<<<1, 1024, 0, stream>>>(deg, rowptr, cursor);
    csr_fill<<<(EE + 255) / 256, 256, 0, stream>>>(edge_index, edge_type, cursor, pack);

    // ---- relation stage ----
    rel_init<<<(BB * RR * DD + 255) / 256, 256, 0, stream>>>(batch_triples, rel_repr);
    for (int l = 0; l < LL; ++l) {
        hipMemsetAsync(rel_agg, 0, sizeof(float) * BB * RR * DD, stream);
        rel_scatter<<<(BB * ERE) / 4, 256, 0, stream>>>(
            rel_edge_index, rel_edge_type, rel_repr,
            rel_emb + l * RT * DD, rel_agg);
        rel_dense<<<(BB * RR) / 4, 256, 0, stream>>>(
            batch_triples, rel_W + l * 2 * DD * DD, rel_b + l * DD,
            rel_g + l * DD, rel_beta + l * DD, rel_repr, rel_agg);
    }
    hipMemsetAsync(x_ent, 0, sizeof(float) * (size_t)BB * NN * DD, stream);
    rel_finish<<<1, 256, 0, stream>>>(batch_triples, rel_repr, query, x_ent);

    // ---- entity stage ----
    for (int l = 0; l < LL; ++l) {
        rel_proj<<<(BB * RR * 64) / 256, 256, 0, stream>>>(
            rel_repr, proj_W1 + l * DD * DD, proj_b1 + l * DD,
            proj_W2 + l * DD * DD, proj_b2 + l * DD, rel_buf);
        gather_agg<<<(BB * NN) / 4, 256, 0, stream>>>(
            rowptr, pack, batch_triples, x_ent, rel_buf, query, agg_ent);
        ent_dense2<<<DENSE_BLOCKS, 256, 0, stream>>>(
            ent_W + l * 2 * DD * DD, ent_b + l * DD, ent_g + l * DD,
            ent_beta + l * DD, x_ent, agg_ent);
    }

    readout<<<BB * KK, 2 * DD, 0, stream>>>(batch_triples, x_ent, query,
                                            mlp_W1, mlp_b1, mlp_W2, mlp_b2,
                                            (float*)d_out);
}